// Round 4
// baseline (673.327 us; speedup 1.0000x reference)
//
#include <hip/hip_runtime.h>
#include <stdint.h>

// ---------------------------------------------------------------------------
// QuantQwenMLP: W4A8 fake-quant SwiGLU MLP.
//   B=4 S=2048 H=2048 I=5632  -> M = B*S = 8192 tokens
// R5 -> R6: flat GEMMs were latency-bound (MfmaUtil 33% == MFMA-floor/dur;
// no BW pipe >52%; 92% L2-hit loads but depth-2 prefetch + ratio 1.33
// MFMA:load can't hide 200-900cyc). Dual: wave tile 64x64 -> 128x64
// (ratio 2.0, W traffic halved, acc 256 regs, 1 wave/SIMD) + in-place
// rolling prefetch depth-4 ksteps (consume-then-overwrite, WAR-safe by
// in-order issue, no double buffer). Single: depth-8 rolling prefetch.
//
// Flat layout for int8 matrix [R][C] (C % 32 == 0), 16-B chunks:
//   chunk(r, c16) -> byte ((r>>5)*(C>>5) + (c16>>1))*1024
//                    + (((c16&1)<<5) | (r&31))*16
// A wave's fragment (row-group g, k-step ks) is the contiguous 1024-B block
//   ((g*(C>>5)+ks)<<10) + lane*16.
// ---------------------------------------------------------------------------

typedef int i32x4  __attribute__((ext_vector_type(4)));
typedef int i32x16 __attribute__((ext_vector_type(16)));

#define MFMA_I8 __builtin_amdgcn_mfma_i32_32x32x32_i8
#define LDF(p, o) (*(const i32x4*)((p) + (o)))

__device__ __forceinline__ int pack4(float4 v, float scale, float qmax) {
    int a = (int)fminf(fmaxf(rintf(v.x / scale), -qmax), qmax);
    int b = (int)fminf(fmaxf(rintf(v.y / scale), -qmax), qmax);
    int c = (int)fminf(fmaxf(rintf(v.z / scale), -qmax), qmax);
    int d = (int)fminf(fmaxf(rintf(v.w / scale), -qmax), qmax);
    return (a & 255) | ((b & 255) << 8) | ((c & 255) << 16) | (d << 24);
}

// ---------------------------------------------------------------------------
// Per-row symmetric fake-quant writing the flat fragment-major layout.
// ---------------------------------------------------------------------------
__global__ __launch_bounds__(256) void quant_rows_shuf(
    const float* __restrict__ src, int8_t* __restrict__ dst,
    float* __restrict__ scales, int C4, float qmax)
{
    __shared__ float4 buf[1408];        // up to 5632 floats = 22.5 KB
    __shared__ float wmax[4];
    const int r = blockIdx.x;
    const float4* s4 = (const float4*)src + (long)r * C4;

    float am = 0.f;
    for (int i = threadIdx.x; i < C4; i += 256) {
        float4 v = s4[i];
        buf[i] = v;
        am = fmaxf(am, fmaxf(fmaxf(fabsf(v.x), fabsf(v.y)),
                             fmaxf(fabsf(v.z), fabsf(v.w))));
    }
    #pragma unroll
    for (int off = 32; off; off >>= 1)
        am = fmaxf(am, __shfl_xor(am, off));
    if ((threadIdx.x & 63) == 0) wmax[threadIdx.x >> 6] = am;
    __syncthreads();
    const float amax = fmaxf(fmaxf(wmax[0], wmax[1]), fmaxf(wmax[2], wmax[3]));
    const float scale = fmaxf(amax / qmax, 1e-8f);
    if (threadIdx.x == 0) scales[r] = scale;

    const int C16 = C4 >> 2;            // 16-B chunks per row
    const int KC  = C4 >> 3;            // 32-B k-steps per row (C>>5)
    const int g   = r >> 5;
    const int rl  = r & 31;
    for (int i = threadIdx.x; i < C16; i += 256) {
        float4 v0 = buf[4*i+0], v1 = buf[4*i+1];
        float4 v2 = buf[4*i+2], v3 = buf[4*i+3];
        i32x4 q;
        q[0] = pack4(v0, scale, qmax);
        q[1] = pack4(v1, scale, qmax);
        q[2] = pack4(v2, scale, qmax);
        q[3] = pack4(v3, scale, qmax);
        size_t off = ((size_t)(g * KC + (i >> 1)) << 10)
                   + ((size_t)((((i & 1) << 5) | rl)) << 4);
        *(i32x4*)(dst + off) = q;
    }
}

// ---------------------------------------------------------------------------
// Fused gate+up int8 GEMM with SwiGLU epilogue (fp32 H out).
// Wave tile 128(M)x64(N); block 256x128 (4 waves). Per k-step: 8 loads,
// 16 MFMA. In-place rolling prefetch, 4 k-steps deep: phase P = {16 MFMA
// consuming set P, then reload set P for iter T+1}.
// ---------------------------------------------------------------------------
__global__ __launch_bounds__(256, 1) void gemm_dual_flat(
    const int8_t* __restrict__ Ash, const float* __restrict__ sA,
    const int8_t* __restrict__ Gsh, const float* __restrict__ sBg,
    const int8_t* __restrict__ Ush, const float* __restrict__ sBu,
    float* __restrict__ H, int M, int N, int K)
{
    const int KC   = K >> 5;            // 64 for K=2048
    const int tid  = threadIdx.x;
    const int lane = tid & 63;
    const int cl   = lane & 31;
    const int kq   = lane >> 5;
    const int wave = tid >> 6;
    const int wm   = (wave >> 1) * 128;
    const int wn   = (wave & 1) * 64;

    // column-band XCD swizzle
    int bx, by;
    {
        const int nwg = gridDim.x * gridDim.y;
        int w = blockIdx.y * gridDim.x + blockIdx.x;
        int t = ((nwg & 7) == 0) ? ((w & 7) * (nwg >> 3) + (w >> 3)) : w;
        bx = t / gridDim.y;
        by = t - bx * gridDim.y;
    }
    const long m0 = (long)by * 256;
    const long n0 = (long)bx * 128;

    const size_t KB = (size_t)KC << 10;     // bytes per 32-row group
    const int8_t* pa = Ash + (size_t)((m0 + wm) >> 5) * KB + lane * 16;
    const int8_t* pg = Gsh + (size_t)((n0 + wn) >> 5) * KB + lane * 16;
    const int8_t* pu = Ush + (size_t)((n0 + wn) >> 5) * KB + lane * 16;

    i32x16 accg[4][2], accu[4][2];
    #pragma unroll
    for (int i = 0; i < 4; ++i)
        #pragma unroll
        for (int j = 0; j < 2; ++j) {
            accg[i][j] = i32x16{0,0,0,0,0,0,0,0,0,0,0,0,0,0,0,0};
            accu[i][j] = i32x16{0,0,0,0,0,0,0,0,0,0,0,0,0,0,0,0};
        }

    // ---- prologue: load k-steps 0..3 (32 loads in flight) ----
#define D_DECL(P) \
    i32x4 a##P##0 = LDF(pa, 0*0 + (P)*1024), \
          a##P##1 = LDF(pa, KB + (P)*1024), \
          a##P##2 = LDF(pa, 2*KB + (P)*1024), \
          a##P##3 = LDF(pa, 3*KB + (P)*1024), \
          g##P##0 = LDF(pg, (P)*1024), \
          g##P##1 = LDF(pg, KB + (P)*1024), \
          u##P##0 = LDF(pu, (P)*1024), \
          u##P##1 = LDF(pu, KB + (P)*1024)
    D_DECL(0); D_DECL(1); D_DECL(2); D_DECL(3);

#define D_PHASE(P) do { \
    accg[0][0] = MFMA_I8(a##P##0, g##P##0, accg[0][0], 0, 0, 0); \
    accg[0][1] = MFMA_I8(a##P##0, g##P##1, accg[0][1], 0, 0, 0); \
    accg[1][0] = MFMA_I8(a##P##1, g##P##0, accg[1][0], 0, 0, 0); \
    accg[1][1] = MFMA_I8(a##P##1, g##P##1, accg[1][1], 0, 0, 0); \
    accg[2][0] = MFMA_I8(a##P##2, g##P##0, accg[2][0], 0, 0, 0); \
    accg[2][1] = MFMA_I8(a##P##2, g##P##1, accg[2][1], 0, 0, 0); \
    accg[3][0] = MFMA_I8(a##P##3, g##P##0, accg[3][0], 0, 0, 0); \
    accg[3][1] = MFMA_I8(a##P##3, g##P##1, accg[3][1], 0, 0, 0); \
    accu[0][0] = MFMA_I8(a##P##0, u##P##0, accu[0][0], 0, 0, 0); \
    accu[0][1] = MFMA_I8(a##P##0, u##P##1, accu[0][1], 0, 0, 0); \
    accu[1][0] = MFMA_I8(a##P##1, u##P##0, accu[1][0], 0, 0, 0); \
    accu[1][1] = MFMA_I8(a##P##1, u##P##1, accu[1][1], 0, 0, 0); \
    accu[2][0] = MFMA_I8(a##P##2, u##P##0, accu[2][0], 0, 0, 0); \
    accu[2][1] = MFMA_I8(a##P##2, u##P##1, accu[2][1], 0, 0, 0); \
    accu[3][0] = MFMA_I8(a##P##3, u##P##0, accu[3][0], 0, 0, 0); \
    accu[3][1] = MFMA_I8(a##P##3, u##P##1, accu[3][1], 0, 0, 0); \
    if (pf) { \
        a##P##0 = LDF(pa, 4096 + (P)*1024); \
        a##P##1 = LDF(pa, KB + 4096 + (P)*1024); \
        a##P##2 = LDF(pa, 2*KB + 4096 + (P)*1024); \
        a##P##3 = LDF(pa, 3*KB + 4096 + (P)*1024); \
        g##P##0 = LDF(pg, 4096 + (P)*1024); \
        g##P##1 = LDF(pg, KB + 4096 + (P)*1024); \
        u##P##0 = LDF(pu, 4096 + (P)*1024); \
        u##P##1 = LDF(pu, KB + 4096 + (P)*1024); \
    } \
} while (0)

    const int NIT = KC >> 2;            // 16 outer iters (4 k-steps each)
    for (int T = 0; T < NIT; ++T) {
        const bool pf = (T + 1) < NIT;
        D_PHASE(0);
        D_PHASE(1);
        D_PHASE(2);
        D_PHASE(3);
        pa += 4096; pg += 4096; pu += 4096;
    }

    // Epilogue. 32x32 C/D layout: col = lane&31, row = (reg&3)+8*(reg>>2)+4*(lane>>5).
    float sg[2], su[2];
    #pragma unroll
    for (int ni = 0; ni < 2; ++ni) {
        long n = n0 + wn + ni * 32 + cl;
        sg[ni] = sBg[n];
        su[ni] = sBu[n];
    }
    #pragma unroll
    for (int mi = 0; mi < 4; ++mi) {
        #pragma unroll
        for (int reg = 0; reg < 16; ++reg) {
            long m = m0 + wm + mi * 32 + (reg & 3) + 8 * (reg >> 2) + 4 * kq;
            float sa = sA[m];
            #pragma unroll
            for (int ni = 0; ni < 2; ++ni) {
                long n = n0 + wn + ni * 32 + cl;
                float g = (float)accg[mi][ni][reg] * sa * sg[ni];
                float u = (float)accu[mi][ni][reg] * sa * su[ni];
                float s = 1.f / (1.f + expf(-g));
                H[m * N + n] = (g * s) * u;
            }
        }
    }
}

// ---------------------------------------------------------------------------
// Single int8 GEMM, flat: out[m][n] = acc * sA[m] * sB[n].
// Wave tile 64x64; in-place rolling prefetch 8 k-steps deep.
// ---------------------------------------------------------------------------
__global__ __launch_bounds__(256, 2) void gemm_single_flat(
    const int8_t* __restrict__ Ash, const float* __restrict__ sA,
    const int8_t* __restrict__ Bsh, const float* __restrict__ sB,
    float* __restrict__ O, int M, int N, int K)
{
    const int KC   = K >> 5;            // 176 for K=5632
    const int tid  = threadIdx.x;
    const int lane = tid & 63;
    const int cl   = lane & 31;
    const int kq   = lane >> 5;
    const int wave = tid >> 6;
    const int wm   = (wave >> 1) * 64;
    const int wn   = (wave & 1) * 64;

    int bx, by;
    {
        const int nwg = gridDim.x * gridDim.y;
        int w = blockIdx.y * gridDim.x + blockIdx.x;
        int t = ((nwg & 7) == 0) ? ((w & 7) * (nwg >> 3) + (w >> 3)) : w;
        bx = t / gridDim.y;
        by = t - bx * gridDim.y;
    }
    const long m0 = (long)by * 128;
    const long n0 = (long)bx * 128;

    const size_t KB = (size_t)KC << 10;
    const int8_t* pa = Ash + (size_t)((m0 + wm) >> 5) * KB + lane * 16;
    const int8_t* pb = Bsh + (size_t)((n0 + wn) >> 5) * KB + lane * 16;

    i32x16 acc[2][2];
    #pragma unroll
    for (int i = 0; i < 2; ++i)
        #pragma unroll
        for (int j = 0; j < 2; ++j)
            acc[i][j] = i32x16{0,0,0,0,0,0,0,0,0,0,0,0,0,0,0,0};

#define S_DECL(P) \
    i32x4 sa##P##0 = LDF(pa, (P)*1024), \
          sa##P##1 = LDF(pa, KB + (P)*1024), \
          sb##P##0 = LDF(pb, (P)*1024), \
          sb##P##1 = LDF(pb, KB + (P)*1024)
    S_DECL(0); S_DECL(1); S_DECL(2); S_DECL(3);
    S_DECL(4); S_DECL(5); S_DECL(6); S_DECL(7);

#define S_PHASE(P) do { \
    acc[0][0] = MFMA_I8(sa##P##0, sb##P##0, acc[0][0], 0, 0, 0); \
    acc[0][1] = MFMA_I8(sa##P##0, sb##P##1, acc[0][1], 0, 0, 0); \
    acc[1][0] = MFMA_I8(sa##P##1, sb##P##0, acc[1][0], 0, 0, 0); \
    acc[1][1] = MFMA_I8(sa##P##1, sb##P##1, acc[1][1], 0, 0, 0); \
    if (pf) { \
        sa##P##0 = LDF(pa, 8192 + (P)*1024); \
        sa##P##1 = LDF(pa, KB + 8192 + (P)*1024); \
        sb##P##0 = LDF(pb, 8192 + (P)*1024); \
        sb##P##1 = LDF(pb, KB + 8192 + (P)*1024); \
    } \
} while (0)

    const int NIT = KC >> 3;            // 22 outer iters (8 k-steps each)
    for (int T = 0; T < NIT; ++T) {
        const bool pf = (T + 1) < NIT;
        S_PHASE(0); S_PHASE(1); S_PHASE(2); S_PHASE(3);
        S_PHASE(4); S_PHASE(5); S_PHASE(6); S_PHASE(7);
        pa += 8192; pb += 8192;
    }

    float sb[2];
    #pragma unroll
    for (int ni = 0; ni < 2; ++ni) sb[ni] = sB[n0 + wn + ni * 32 + cl];
    #pragma unroll
    for (int mi = 0; mi < 2; ++mi) {
        #pragma unroll
        for (int reg = 0; reg < 16; ++reg) {
            long m = m0 + wm + mi * 32 + (reg & 3) + 8 * (reg >> 2) + 4 * kq;
            float sa = sA[m];
            #pragma unroll
            for (int ni = 0; ni < 2; ++ni) {
                long n = n0 + wn + ni * 32 + cl;
                O[m * N + n] = (float)acc[mi][ni][reg] * sa * sb[ni];
            }
        }
    }
}

// ---------------------------------------------------------------------------

extern "C" void kernel_launch(void* const* d_in, const int* in_sizes, int n_in,
                              void* d_out, int out_size, void* d_ws, size_t ws_size,
                              hipStream_t stream)
{
    const float* x  = (const float*)d_in[0];   // [4,2048,2048]
    const float* Wg = (const float*)d_in[1];   // [5632,2048]
    const float* Wu = (const float*)d_in[2];   // [5632,2048]
    const float* Wd = (const float*)d_in[3];   // [2048,5632]
    float* out = (float*)d_out;                // [4,2048,2048] fp32

    const int M  = 8192;      // B*S
    const int H  = 2048;
    const int I  = 5632;

    // ---- fixed workspace regions (~49.1 MiB) ----
    char* p = (char*)d_ws;
    int8_t* xq  = (int8_t*)p; p += (size_t)M * H;
    float*  sx  = (float*)p;  p += (size_t)M * 4;
    int8_t* wgq = (int8_t*)p; p += (size_t)I * H;
    float*  swg = (float*)p;  p += (size_t)I * 4;
    int8_t* wuq = (int8_t*)p; p += (size_t)I * H;
    float*  swu = (float*)p;  p += (size_t)I * 4;
    int8_t* wdq = (int8_t*)p; p += (size_t)H * I;
    float*  swd = (float*)p;  p += (size_t)H * 4;
    float*  sh  = (float*)p;  p += (size_t)M * 4;
    const size_t fixed_bytes = (size_t)(p - (char*)d_ws);

    // ---- largest M-chunk whose h (fp32) + hq (int8) fit ws_size ----
    int Mc = 256;
    for (int cand = 8192; cand >= 256; cand >>= 1) {
        size_t need = fixed_bytes + (size_t)cand * I * 5;
        if (need <= ws_size) { Mc = cand; break; }
    }
    float*  hbuf = (float*)p;  p += (size_t)Mc * I * 4;
    int8_t* hq   = (int8_t*)p;

    // 1) quantize weights (qmax=7) and activations (qmax=127) into flat layout
    quant_rows_shuf<<<I, 256, 0, stream>>>(Wg, wgq, swg, H / 4, 7.f);
    quant_rows_shuf<<<I, 256, 0, stream>>>(Wu, wuq, swu, H / 4, 7.f);
    quant_rows_shuf<<<H, 256, 0, stream>>>(Wd, wdq, swd, I / 4, 7.f);
    quant_rows_shuf<<<M, 256, 0, stream>>>(x,  xq,  sx,  H / 4, 127.f);

    // 2) per M-chunk: gate+up GEMM + SwiGLU -> h ; quantize h ; down-proj
    for (int m0 = 0; m0 < M; m0 += Mc) {
        gemm_dual_flat<<<dim3(I / 128, Mc / 256), 256, 0, stream>>>(
            xq + (size_t)m0 * H, sx + m0, wgq, swg, wuq, swu,
            hbuf, Mc, I, H);
        quant_rows_shuf<<<Mc, 256, 0, stream>>>(hbuf, hq, sh + m0, I / 4, 127.f);
        gemm_single_flat<<<dim3(H / 128, Mc / 128), 256, 0, stream>>>(
            hq, sh + m0, wdq, swd, out + (size_t)m0 * H, Mc, H, I);
    }
}